// Round 24
// baseline (172.695 us; speedup 1.0000x reference)
//
#include <hip/hip_runtime.h>

#define F_IN 256
#define HID 16
#define NCLS 8
#define BSH 9
#define NPB 512               // nodes per bin
#define MAXBINS 256
#define BCAP 18432u           // per-bin edge capacity (mean 16384, +16 sigma)
#define TILE 8192             // edges per binA block (512 threads)
#define WIN 8
#define GROWS 64              // gemm1 rows per block
#define APITCH 280            // fp16 pitch: <=2-way alias on ds_read_b128

typedef float f4v __attribute__((ext_vector_type(4)));
typedef float f32x4 __attribute__((ext_vector_type(4)));
typedef unsigned u4v __attribute__((ext_vector_type(4)));
typedef unsigned u2v __attribute__((ext_vector_type(2)));
typedef _Float16 h2v __attribute__((ext_vector_type(2)));
typedef _Float16 f16x4 __attribute__((ext_vector_type(4)));
typedef _Float16 f16x8 __attribute__((ext_vector_type(8)));

// ---------- init: bin cursors + packed W1 B-fragments + zero cg/out ----------
__global__ void k_init(unsigned* __restrict__ binCur, int nbins,
                       const float* __restrict__ W1, _Float16* __restrict__ wfrag,
                       float* __restrict__ cg, int g,
                       float* __restrict__ out, int osz) {
    int t = threadIdx.x;
    if (t < nbins) binCur[t] = (unsigned)t * BCAP;
    if (t < 64) {
        int col = t & 15, k0 = (t >> 4) * 8;
#pragma unroll
        for (int kc = 0; kc < 8; ++kc) {
            f16x8 v;
#pragma unroll
            for (int j = 0; j < 8; ++j)
                v[j] = (_Float16)W1[(kc * 32 + k0 + j) * HID + col];
            *(f16x8*)&wfrag[((size_t)t * 8 + kc) * 8] = v;
        }
    }
    for (int i = t; i < g; i += 256) cg[i] = 0.f;
    for (int i = t; i < osz; i += 256) out[i] = 0.f;
}

// ---------- pass A: bin edges by dst>>9 (contiguous runs) --------------------
__global__ void __launch_bounds__(512) k_binA(const int* __restrict__ src,
                                              const int* __restrict__ dst, int e,
                                              unsigned* __restrict__ binCur,
                                              unsigned* __restrict__ binbuf) {
    __shared__ unsigned scnt[MAXBINS], lbase[MAXBINS], gbase[MAXBINS];
    __shared__ unsigned sbuf[TILE];
    __shared__ unsigned char sbin[TILE];
    int t = threadIdx.x;
    if (t < MAXBINS) scnt[t] = 0u;
    __syncthreads();
    int base = blockIdx.x * TILE;
    unsigned ent[16], rank[16];
    int ebin[16];
#pragma unroll
    for (int i = 0; i < 16; ++i) {
        int j = base + t + i * 512;
        ebin[i] = -1;
        if (j < e) {
            int d = __builtin_nontemporal_load(&dst[j]);
            int s = __builtin_nontemporal_load(&src[j]);
            ent[i] = ((unsigned)s << BSH) | ((unsigned)d & (NPB - 1));
            ebin[i] = d >> BSH;
            rank[i] = atomicAdd(&scnt[ebin[i]], 1u);
        }
    }
    __syncthreads();
    if (t == 0) {
        unsigned run = 0;
        for (int b = 0; b < MAXBINS; ++b) { lbase[b] = run; run += scnt[b]; }
    }
    __syncthreads();
    if (t < MAXBINS && scnt[t] > 0u) gbase[t] = atomicAdd(&binCur[t], scnt[t]);
    __syncthreads();
#pragma unroll
    for (int i = 0; i < 16; ++i)
        if (ebin[i] >= 0) {
            unsigned p = lbase[ebin[i]] + rank[i];
            sbuf[p] = ent[i];
            sbin[p] = (unsigned char)ebin[i];
        }
    __syncthreads();
    int total = e - base; if (total > TILE) total = TILE;
    for (int idx = t; idx < total; idx += 512) {
        int b = sbin[idx];
        __builtin_nontemporal_store(sbuf[idx], &binbuf[gbase[b] + ((unsigned)idx - lbase[b])]);
    }
}

// ---------- pass B: monolithic per-bin counting sort (LDS-staged) ------------
__global__ void __launch_bounds__(256) k_binB(const unsigned* __restrict__ binbuf,
                                              const unsigned* __restrict__ binCur,
                                              int n,
                                              unsigned* __restrict__ srcs,
                                              unsigned* __restrict__ off,
                                              unsigned* __restrict__ degc) {
    __shared__ unsigned sbuf[BCAP];   // 72 KB
    __shared__ unsigned hist[NPB];
    __shared__ unsigned pref[NPB];
    __shared__ unsigned s1[256];
    int t = threadIdx.x;
    int b = blockIdx.x;
    unsigned base = (unsigned)b * BCAP;
    unsigned cnt = binCur[b] - base;
    for (int i = t; i < NPB; i += 256) hist[i] = 0u;
    __syncthreads();
    for (unsigned j = t; j < cnt; j += 256) {
        unsigned v = __builtin_nontemporal_load(&binbuf[base + j]);
        sbuf[j] = v;
        atomicAdd(&hist[v & (NPB - 1)], 1u);
    }
    __syncthreads();
    unsigned h0 = hist[2 * t], h1 = hist[2 * t + 1];
    unsigned pair = h0 + h1;
    s1[t] = pair;
    __syncthreads();
    for (int o = 1; o < 256; o <<= 1) {
        unsigned v = (t >= o) ? s1[t - o] : 0u;
        __syncthreads();
        s1[t] += v;
        __syncthreads();
    }
    unsigned exc = s1[t] - pair;
    pref[2 * t] = exc;
    pref[2 * t + 1] = exc + h0;
    __syncthreads();
    int dbase = b << BSH;
    for (int i = t; i < NPB; i += 256) {
        int d = dbase + i;
        if (d < n) { off[d] = base + pref[i]; degc[d] = hist[i]; }
    }
    __syncthreads();
    for (int i = t; i < NPB; i += 256) hist[i] = 0u;  // reuse as cursors
    __syncthreads();
    for (unsigned j = t; j < cnt; j += 256) {
        unsigned v = sbuf[j];
        unsigned dl = v & (NPB - 1);
        unsigned r = atomicAdd(&hist[dl], 1u);
        srcs[base + pref[dl] + r] = v >> BSH;
    }
}

// ---------- GEMM1 via MFMA: t1h[n][16] fp16 = (x@W1)*rsqrt(deg+1) ------------
__global__ void __launch_bounds__(256) k_gemm1(const float* __restrict__ x,
                                               const _Float16* __restrict__ wfrag,
                                               const unsigned* __restrict__ degc,
                                               _Float16* __restrict__ t1h, int n) {
    __shared__ _Float16 xs[4][16 * APITCH];  // 35840 B
    int t = threadIdx.x;
    int lane = t & 63;
    int wv = t >> 6;
    int col = lane & 15;
    int k0 = (lane >> 4) * 8;
    f16x8 bfrag[8];
#pragma unroll
    for (int kc = 0; kc < 8; ++kc)
        bfrag[kc] = *(const f16x8*)&wfrag[((size_t)lane * 8 + kc) * 8];
    int rbase = blockIdx.x * GROWS;
    int nrows = n - rbase; if (nrows > GROWS) nrows = GROWS;
#pragma unroll
    for (int it = 0; it < GROWS * 64 / 256; ++it) {
        int q = t + it * 256;           // float4 index: 64 per row
        int row = q >> 6, c4 = q & 63;
        if (row < nrows) {
            f4v v = __builtin_nontemporal_load(
                &((const f4v*)(x + (size_t)(rbase + row) * F_IN))[c4]);
            f16x4 hv;
            hv[0] = (_Float16)v[0]; hv[1] = (_Float16)v[1];
            hv[2] = (_Float16)v[2]; hv[3] = (_Float16)v[3];
            *(f16x4*)&xs[row >> 4][(row & 15) * APITCH + c4 * 4] = hv;
        }
    }
    __syncthreads();
    f32x4 acc = {0.f, 0.f, 0.f, 0.f};
    const _Float16* tile = xs[wv];
    int arow = lane & 15;
#pragma unroll
    for (int kc = 0; kc < 8; ++kc) {
        f16x8 afrag = *(const f16x8*)&tile[arow * APITCH + kc * 32 + k0];
        acc = __builtin_amdgcn_mfma_f32_16x16x32_f16(afrag, bfrag[kc], acc, 0, 0, 0);
    }
    int r0 = (lane >> 4) * 4;
#pragma unroll
    for (int reg = 0; reg < 4; ++reg) {
        int grow = rbase + wv * 16 + r0 + reg;
        if (grow < n) {
            float v = acc[reg] * rsqrtf((float)(degc[grow] + 1u));
            t1h[(size_t)grow * HID + col] = (_Float16)v;
        }
    }
}

#define ACC8(V) { cv.u = (V)[0]; a0 += (float)cv.h[0]; a1 += (float)cv.h[1]; \
                  cv.u = (V)[1]; a2 += (float)cv.h[0]; a3 += (float)cv.h[1]; \
                  cv.u = (V)[2]; a4 += (float)cv.h[0]; a5 += (float)cv.h[1]; \
                  cv.u = (V)[3]; a6 += (float)cv.h[0]; a7 += (float)cv.h[1]; }

// ---------- conv1 + GEMM2 fused: 4 lanes/dst, u4v (16B) gathers --------------
__global__ void __launch_bounds__(256) k_agg1g2(const unsigned* __restrict__ srcs,
                                                const unsigned* __restrict__ off,
                                                const unsigned* __restrict__ degc,
                                                const u4v* __restrict__ t1x,  // [n*2]
                                                const float* __restrict__ b1,
                                                const float* __restrict__ W2,
                                                unsigned* __restrict__ t2h, int n) {
    __shared__ float w2s[HID * NCLS];
    __shared__ float b1s[HID];
    int t = threadIdx.x;
    if (t < HID * NCLS) w2s[t] = W2[t];
    if (t < HID) b1s[t] = b1[t];
    __syncthreads();
    int d = blockIdx.x * 64 + (t >> 2);
    if (d >= n) return;            // uniform per 4-lane group
    int half = t & 1;              // which 16B half of the 32B row (features 8*half..)
    int pr = (t >> 1) & 1;         // edge parity
    unsigned p = off[d];
    unsigned c = degc[d];
    float a0 = 0.f, a1 = 0.f, a2 = 0.f, a3 = 0.f;
    float a4 = 0.f, a5 = 0.f, a6 = 0.f, a7 = 0.f;
    union { unsigned u; h2v h; } cv;
    unsigned i = pr;
    for (; i + 14 < c; i += 16) {
        u4v w0 = t1x[(size_t)srcs[p + i] * 2 + half];
        u4v w1 = t1x[(size_t)srcs[p + i + 2] * 2 + half];
        u4v w2 = t1x[(size_t)srcs[p + i + 4] * 2 + half];
        u4v w3 = t1x[(size_t)srcs[p + i + 6] * 2 + half];
        u4v w4 = t1x[(size_t)srcs[p + i + 8] * 2 + half];
        u4v w5 = t1x[(size_t)srcs[p + i + 10] * 2 + half];
        u4v w6 = t1x[(size_t)srcs[p + i + 12] * 2 + half];
        u4v w7 = t1x[(size_t)srcs[p + i + 14] * 2 + half];
        ACC8(w0) ACC8(w1) ACC8(w2) ACC8(w3)
        ACC8(w4) ACC8(w5) ACC8(w6) ACC8(w7)
    }
    for (; i + 6 < c; i += 8) {
        u4v w0 = t1x[(size_t)srcs[p + i] * 2 + half];
        u4v w1 = t1x[(size_t)srcs[p + i + 2] * 2 + half];
        u4v w2 = t1x[(size_t)srcs[p + i + 4] * 2 + half];
        u4v w3 = t1x[(size_t)srcs[p + i + 6] * 2 + half];
        ACC8(w0) ACC8(w1) ACC8(w2) ACC8(w3)
    }
    for (; i + 2 < c; i += 4) {
        u4v w0 = t1x[(size_t)srcs[p + i] * 2 + half];
        u4v w1 = t1x[(size_t)srcs[p + i + 2] * 2 + half];
        ACC8(w0) ACC8(w1)
    }
    if (i < c) {
        u4v w0 = t1x[(size_t)srcs[p + i] * 2 + half];
        ACC8(w0)
    }
    // merge edge-parity halves (partner differs in bit 1; all 4 lanes alive)
    a0 += __shfl_xor(a0, 2, 64);
    a1 += __shfl_xor(a1, 2, 64);
    a2 += __shfl_xor(a2, 2, 64);
    a3 += __shfl_xor(a3, 2, 64);
    a4 += __shfl_xor(a4, 2, 64);
    a5 += __shfl_xor(a5, 2, 64);
    a6 += __shfl_xor(a6, 2, 64);
    a7 += __shfl_xor(a7, 2, 64);
    // self loop (both parity lanes compute identically)
    u4v sl = t1x[(size_t)d * 2 + half];
    ACC8(sl)
    float di = rsqrtf((float)(c + 1u));
    int k0 = 8 * half;
    float h[8];
    h[0] = fmaxf(di * a0 + b1s[k0 + 0], 0.f);
    h[1] = fmaxf(di * a1 + b1s[k0 + 1], 0.f);
    h[2] = fmaxf(di * a2 + b1s[k0 + 2], 0.f);
    h[3] = fmaxf(di * a3 + b1s[k0 + 3], 0.f);
    h[4] = fmaxf(di * a4 + b1s[k0 + 4], 0.f);
    h[5] = fmaxf(di * a5 + b1s[k0 + 5], 0.f);
    h[6] = fmaxf(di * a6 + b1s[k0 + 6], 0.f);
    h[7] = fmaxf(di * a7 + b1s[k0 + 7], 0.f);
    // GEMM2 partials: this lane covers k = k0..k0+7
    float o[NCLS];
#pragma unroll
    for (int cc = 0; cc < NCLS; ++cc) {
        float s = 0.f;
#pragma unroll
        for (int j = 0; j < 8; ++j) s += h[j] * w2s[(k0 + j) * NCLS + cc];
        o[cc] = s;
    }
    // combine the two half-row lanes (partner differs in bit 0)
#pragma unroll
    for (int cc = 0; cc < NCLS; ++cc) o[cc] += __shfl_xor(o[cc], 1, 64);
    if (pr == 0) {
        // lane half writes classes 4*half..4*half+3 (u2v)
        int f0 = 4 * half;
        union { unsigned u; h2v h; } pa, pb;
        pa.h[0] = (_Float16)(o[f0 + 0] * di); pa.h[1] = (_Float16)(o[f0 + 1] * di);
        pb.h[0] = (_Float16)(o[f0 + 2] * di); pb.h[1] = (_Float16)(o[f0 + 3] * di);
        u2v pk; pk[0] = pa.u; pk[1] = pb.u;
        *(u2v*)&t2h[(size_t)d * 4 + half * 2] = pk;
    }
}

// ---------- conv2: 2 lanes/dst, one u4v row per edge, fused mean-pool --------
__global__ void __launch_bounds__(256) k_agg2pool(const unsigned* __restrict__ srcs,
                                                  const unsigned* __restrict__ off,
                                                  const unsigned* __restrict__ degc,
                                                  const u4v* __restrict__ t2x,  // [n]
                                                  const float* __restrict__ b2,
                                                  const int* __restrict__ batch,
                                                  float* __restrict__ out,
                                                  float* __restrict__ cg, int n) {
    __shared__ float wacc[WIN * NCLS];
    __shared__ float wcnt[WIN];
    __shared__ int gb_s;
    int t = threadIdx.x;
    int bbase = blockIdx.x * 128;
    if (t < WIN * NCLS) wacc[t] = 0.f;
    if (t < WIN) wcnt[t] = 0.f;
    if (t == 0) gb_s = batch[bbase < n ? bbase : (n - 1)];
    __syncthreads();
    int d = bbase + (t >> 1);
    int pr = t & 1;                // edge parity
    if (d < n) {
        unsigned p = off[d];
        unsigned c = degc[d];
        float a0 = 0.f, a1 = 0.f, a2 = 0.f, a3 = 0.f;
        float a4 = 0.f, a5 = 0.f, a6 = 0.f, a7 = 0.f;
        union { unsigned u; h2v h; } cv;
        unsigned i = pr;
        for (; i + 14 < c; i += 16) {
            u4v w0 = t2x[srcs[p + i]];
            u4v w1 = t2x[srcs[p + i + 2]];
            u4v w2 = t2x[srcs[p + i + 4]];
            u4v w3 = t2x[srcs[p + i + 6]];
            u4v w4 = t2x[srcs[p + i + 8]];
            u4v w5 = t2x[srcs[p + i + 10]];
            u4v w6 = t2x[srcs[p + i + 12]];
            u4v w7 = t2x[srcs[p + i + 14]];
            ACC8(w0) ACC8(w1) ACC8(w2) ACC8(w3)
            ACC8(w4) ACC8(w5) ACC8(w6) ACC8(w7)
        }
        for (; i + 6 < c; i += 8) {
            u4v w0 = t2x[srcs[p + i]];
            u4v w1 = t2x[srcs[p + i + 2]];
            u4v w2 = t2x[srcs[p + i + 4]];
            u4v w3 = t2x[srcs[p + i + 6]];
            ACC8(w0) ACC8(w1) ACC8(w2) ACC8(w3)
        }
        for (; i + 2 < c; i += 4) {
            u4v w0 = t2x[srcs[p + i]];
            u4v w1 = t2x[srcs[p + i + 2]];
            ACC8(w0) ACC8(w1)
        }
        if (i < c) {
            u4v w0 = t2x[srcs[p + i]];
            ACC8(w0)
        }
        // merge parity (partner differs in bit 0)
        a0 += __shfl_xor(a0, 1, 64);
        a1 += __shfl_xor(a1, 1, 64);
        a2 += __shfl_xor(a2, 1, 64);
        a3 += __shfl_xor(a3, 1, 64);
        a4 += __shfl_xor(a4, 1, 64);
        a5 += __shfl_xor(a5, 1, 64);
        a6 += __shfl_xor(a6, 1, 64);
        a7 += __shfl_xor(a7, 1, 64);
        if (pr == 0) {
            u4v sl = t2x[d];  // self loop
            ACC8(sl)
            float di = rsqrtf((float)(c + 1u));
            float v[8] = {di * a0 + b2[0], di * a1 + b2[1], di * a2 + b2[2],
                          di * a3 + b2[3], di * a4 + b2[4], di * a5 + b2[5],
                          di * a6 + b2[6], di * a7 + b2[7]};
            int g = batch[d];
            int gi = g - gb_s;
            if (gi < WIN) {
#pragma unroll
                for (int f = 0; f < 8; ++f) atomicAdd(&wacc[gi * NCLS + f], v[f]);
                atomicAdd(&wcnt[gi], 1.f);
            } else {
#pragma unroll
                for (int f = 0; f < 8; ++f) atomicAdd(&out[(size_t)g * NCLS + f], v[f]);
                atomicAdd(&cg[g], 1.f);
            }
        }
    }
    __syncthreads();
    if (t < WIN * NCLS && wcnt[t >> 3] > 0.f)
        atomicAdd(&out[(size_t)(gb_s + (t >> 3)) * NCLS + (t & 7)], wacc[t]);
    if (t < WIN && wcnt[t] > 0.f) atomicAdd(&cg[gb_s + t], wcnt[t]);
}

__global__ void k_div(float* __restrict__ out, const float* __restrict__ cg, int total) {
    int i = blockIdx.x * blockDim.x + threadIdx.x;
    if (i < total) out[i] /= fmaxf(cg[i / NCLS], 1.0f);
}

extern "C" void kernel_launch(void* const* d_in, const int* in_sizes, int n_in,
                              void* d_out, int out_size, void* d_ws, size_t ws_size,
                              hipStream_t stream) {
    const float* x = (const float*)d_in[0];
    const int* ei = (const int*)d_in[1];
    const int* batch = (const int*)d_in[2];
    const float* W1 = (const float*)d_in[4];
    const float* b1 = (const float*)d_in[5];
    const float* W2 = (const float*)d_in[6];
    const float* b2 = (const float*)d_in[7];

    int n = in_sizes[0] / F_IN;
    int e = in_sizes[1] / 2;
    int g = out_size / NCLS;
    const int* src = ei;
    const int* dst = ei + e;
    int nbins = (n + NPB - 1) >> BSH;  // 196 for n=100000

    char* w = (char*)d_ws;
    unsigned* binCur = (unsigned*)w; w += (size_t)MAXBINS * 4;
    unsigned* degc   = (unsigned*)w; w += (size_t)n * 4;
    unsigned* off    = (unsigned*)w; w += (size_t)n * 4;
    w = (char*)(((size_t)w + 15) & ~(size_t)15);
    unsigned* t1h    = (unsigned*)w; w += (size_t)n * 8 * 4;   // fp16 pairs, 3.2 MB
    unsigned* t2h    = (unsigned*)w; w += (size_t)n * 4 * 4;   // fp16 pairs, 1.6 MB
    _Float16* wfrag  = (_Float16*)w; w += (size_t)64 * 8 * 8 * 2;  // 8 KB
    float* cg        = (float*)w;    w += (size_t)g * 4;
    w = (char*)(((size_t)w + 255) & ~(size_t)255);
    unsigned* binbuf = (unsigned*)w; w += (size_t)nbins * BCAP * 4;  // 14.5 MB
    unsigned* srcs   = (unsigned*)w; w += (size_t)nbins * BCAP * 4;  // 14.5 MB

    k_init<<<1, 256, 0, stream>>>(binCur, nbins, W1, wfrag, cg, g, (float*)d_out, out_size);
    k_binA<<<(e + TILE - 1) / TILE, 512, 0, stream>>>(src, dst, e, binCur, binbuf);
    k_binB<<<nbins, 256, 0, stream>>>(binbuf, binCur, n, srcs, off, degc);
    k_gemm1<<<(n + GROWS - 1) / GROWS, 256, 0, stream>>>(x, wfrag, degc, (_Float16*)t1h, n);
    k_agg1g2<<<(n + 63) / 64, 256, 0, stream>>>(srcs, off, degc, (const u4v*)t1h,
                                                b1, W2, t2h, n);
    k_agg2pool<<<(n + 127) / 128, 256, 0, stream>>>(srcs, off, degc, (const u4v*)t2h,
                                                    b2, batch, (float*)d_out, cg, n);
    k_div<<<(out_size + 255) / 256, 256, 0, stream>>>((float*)d_out, cg, out_size);
}

// Round 25
// 160.234 us; speedup vs baseline: 1.0778x; 1.0778x over previous
//
#include <hip/hip_runtime.h>

#define F_IN 256
#define HID 16
#define NCLS 8
#define BSH 9
#define NPB 512               // nodes per bin
#define MAXBINS 256
#define BCAP 18432u           // per-bin edge capacity (mean 16384, +16 sigma)
#define TILE 8192             // edges per binA block (512 threads)
#define WIN 8
#define GROWS 64              // gemm1 rows per block
#define APITCH 280            // fp16 pitch: <=2-way alias on ds_read_b128

typedef float f4v __attribute__((ext_vector_type(4)));
typedef float f32x4 __attribute__((ext_vector_type(4)));
typedef _Float16 h2v __attribute__((ext_vector_type(2)));
typedef _Float16 f16x4 __attribute__((ext_vector_type(4)));
typedef _Float16 f16x8 __attribute__((ext_vector_type(8)));

// ---------- init: bin cursors + packed W1 B-fragments + zero cg/out ----------
__global__ void k_init(unsigned* __restrict__ binCur, int nbins,
                       const float* __restrict__ W1, _Float16* __restrict__ wfrag,
                       float* __restrict__ cg, int g,
                       float* __restrict__ out, int osz) {
    int t = threadIdx.x;
    if (t < nbins) binCur[t] = (unsigned)t * BCAP;
    if (t < 64) {
        int col = t & 15, k0 = (t >> 4) * 8;
#pragma unroll
        for (int kc = 0; kc < 8; ++kc) {
            f16x8 v;
#pragma unroll
            for (int j = 0; j < 8; ++j)
                v[j] = (_Float16)W1[(kc * 32 + k0 + j) * HID + col];
            *(f16x8*)&wfrag[((size_t)t * 8 + kc) * 8] = v;
        }
    }
    for (int i = t; i < g; i += 256) cg[i] = 0.f;
    for (int i = t; i < osz; i += 256) out[i] = 0.f;
}

// ---------- pass A: bin edges by dst>>9 (contiguous runs) --------------------
__global__ void __launch_bounds__(512) k_binA(const int* __restrict__ src,
                                              const int* __restrict__ dst, int e,
                                              unsigned* __restrict__ binCur,
                                              unsigned* __restrict__ binbuf) {
    __shared__ unsigned scnt[MAXBINS], lbase[MAXBINS], gbase[MAXBINS];
    __shared__ unsigned sbuf[TILE];
    __shared__ unsigned char sbin[TILE];
    int t = threadIdx.x;
    if (t < MAXBINS) scnt[t] = 0u;
    __syncthreads();
    int base = blockIdx.x * TILE;
    unsigned ent[16], rank[16];
    int ebin[16];
#pragma unroll
    for (int i = 0; i < 16; ++i) {
        int j = base + t + i * 512;
        ebin[i] = -1;
        if (j < e) {
            int d = __builtin_nontemporal_load(&dst[j]);
            int s = __builtin_nontemporal_load(&src[j]);
            ent[i] = ((unsigned)s << BSH) | ((unsigned)d & (NPB - 1));
            ebin[i] = d >> BSH;
            rank[i] = atomicAdd(&scnt[ebin[i]], 1u);
        }
    }
    __syncthreads();
    if (t == 0) {
        unsigned run = 0;
        for (int b = 0; b < MAXBINS; ++b) { lbase[b] = run; run += scnt[b]; }
    }
    __syncthreads();
    if (t < MAXBINS && scnt[t] > 0u) gbase[t] = atomicAdd(&binCur[t], scnt[t]);
    __syncthreads();
#pragma unroll
    for (int i = 0; i < 16; ++i)
        if (ebin[i] >= 0) {
            unsigned p = lbase[ebin[i]] + rank[i];
            sbuf[p] = ent[i];
            sbin[p] = (unsigned char)ebin[i];
        }
    __syncthreads();
    int total = e - base; if (total > TILE) total = TILE;
    for (int idx = t; idx < total; idx += 512) {
        int b = sbin[idx];
        __builtin_nontemporal_store(sbuf[idx], &binbuf[gbase[b] + ((unsigned)idx - lbase[b])]);
    }
}

// ---------- pass B: monolithic per-bin counting sort (LDS-staged) ------------
__global__ void __launch_bounds__(256) k_binB(const unsigned* __restrict__ binbuf,
                                              const unsigned* __restrict__ binCur,
                                              int n,
                                              unsigned* __restrict__ srcs,
                                              unsigned* __restrict__ off,
                                              unsigned* __restrict__ degc) {
    __shared__ unsigned sbuf[BCAP];   // 72 KB
    __shared__ unsigned hist[NPB];
    __shared__ unsigned pref[NPB];
    __shared__ unsigned s1[256];
    int t = threadIdx.x;
    int b = blockIdx.x;
    unsigned base = (unsigned)b * BCAP;
    unsigned cnt = binCur[b] - base;
    for (int i = t; i < NPB; i += 256) hist[i] = 0u;
    __syncthreads();
    for (unsigned j = t; j < cnt; j += 256) {
        unsigned v = __builtin_nontemporal_load(&binbuf[base + j]);
        sbuf[j] = v;
        atomicAdd(&hist[v & (NPB - 1)], 1u);
    }
    __syncthreads();
    unsigned h0 = hist[2 * t], h1 = hist[2 * t + 1];
    unsigned pair = h0 + h1;
    s1[t] = pair;
    __syncthreads();
    for (int o = 1; o < 256; o <<= 1) {
        unsigned v = (t >= o) ? s1[t - o] : 0u;
        __syncthreads();
        s1[t] += v;
        __syncthreads();
    }
    unsigned exc = s1[t] - pair;
    pref[2 * t] = exc;
    pref[2 * t + 1] = exc + h0;
    __syncthreads();
    int dbase = b << BSH;
    for (int i = t; i < NPB; i += 256) {
        int d = dbase + i;
        if (d < n) { off[d] = base + pref[i]; degc[d] = hist[i]; }
    }
    __syncthreads();
    for (int i = t; i < NPB; i += 256) hist[i] = 0u;  // reuse as cursors
    __syncthreads();
    for (unsigned j = t; j < cnt; j += 256) {
        unsigned v = sbuf[j];
        unsigned dl = v & (NPB - 1);
        unsigned r = atomicAdd(&hist[dl], 1u);
        srcs[base + pref[dl] + r] = v >> BSH;
    }
}

// ---------- GEMM1 via MFMA: t1h[n][16] fp16 = (x@W1)*rsqrt(deg+1) ------------
__global__ void __launch_bounds__(256) k_gemm1(const float* __restrict__ x,
                                               const _Float16* __restrict__ wfrag,
                                               const unsigned* __restrict__ degc,
                                               _Float16* __restrict__ t1h, int n) {
    __shared__ _Float16 xs[4][16 * APITCH];  // 35840 B
    int t = threadIdx.x;
    int lane = t & 63;
    int wv = t >> 6;
    int col = lane & 15;
    int k0 = (lane >> 4) * 8;
    f16x8 bfrag[8];
#pragma unroll
    for (int kc = 0; kc < 8; ++kc)
        bfrag[kc] = *(const f16x8*)&wfrag[((size_t)lane * 8 + kc) * 8];
    int rbase = blockIdx.x * GROWS;
    int nrows = n - rbase; if (nrows > GROWS) nrows = GROWS;
#pragma unroll
    for (int it = 0; it < GROWS * 64 / 256; ++it) {
        int q = t + it * 256;           // float4 index: 64 per row
        int row = q >> 6, c4 = q & 63;
        if (row < nrows) {
            f4v v = __builtin_nontemporal_load(
                &((const f4v*)(x + (size_t)(rbase + row) * F_IN))[c4]);
            f16x4 hv;
            hv[0] = (_Float16)v[0]; hv[1] = (_Float16)v[1];
            hv[2] = (_Float16)v[2]; hv[3] = (_Float16)v[3];
            *(f16x4*)&xs[row >> 4][(row & 15) * APITCH + c4 * 4] = hv;
        }
    }
    __syncthreads();
    f32x4 acc = {0.f, 0.f, 0.f, 0.f};
    const _Float16* tile = xs[wv];
    int arow = lane & 15;
#pragma unroll
    for (int kc = 0; kc < 8; ++kc) {
        f16x8 afrag = *(const f16x8*)&tile[arow * APITCH + kc * 32 + k0];
        acc = __builtin_amdgcn_mfma_f32_16x16x32_f16(afrag, bfrag[kc], acc, 0, 0, 0);
    }
    int r0 = (lane >> 4) * 4;
#pragma unroll
    for (int reg = 0; reg < 4; ++reg) {
        int grow = rbase + wv * 16 + r0 + reg;
        if (grow < n) {
            float v = acc[reg] * rsqrtf((float)(degc[grow] + 1u));
            t1h[(size_t)grow * HID + col] = (_Float16)v;
        }
    }
}

// ---------- conv1 + GEMM2 fused: 8 lanes/dst, uint2 gathers, 8-deep ----------
__global__ void __launch_bounds__(256) k_agg1g2(const unsigned* __restrict__ srcs,
                                                const unsigned* __restrict__ off,
                                                const unsigned* __restrict__ degc,
                                                const uint2* __restrict__ t1q,  // [n*4] uint2
                                                const float* __restrict__ b1,
                                                const float* __restrict__ W2,
                                                unsigned* __restrict__ t2h, int n) {
    __shared__ float w2s[HID * NCLS];
    __shared__ float b1s[HID];
    int t = threadIdx.x;
    if (t < HID * NCLS) w2s[t] = W2[t];
    if (t < HID) b1s[t] = b1[t];
    __syncthreads();
    int d = blockIdx.x * 32 + (t >> 3);
    if (d >= n) return;            // uniform per 8-lane group
    int q4 = t & 3;                // uint2 index within 32B row (features 4q4..4q4+3)
    int pr = (t >> 2) & 1;         // edge parity
    unsigned p = off[d];
    unsigned c = degc[d];
    float a0 = 0.f, a1 = 0.f, a2 = 0.f, a3 = 0.f;
    union { unsigned u; h2v h; } cv;
    unsigned i = pr;
    for (; i + 14 < c; i += 16) {
        unsigned s0 = srcs[p + i],      s1 = srcs[p + i + 2];
        unsigned s2 = srcs[p + i + 4],  s3 = srcs[p + i + 6];
        unsigned s4 = srcs[p + i + 8],  s5 = srcs[p + i + 10];
        unsigned s6 = srcs[p + i + 12], s7 = srcs[p + i + 14];
        uint2 w0 = t1q[(size_t)s0 * 4 + q4];
        uint2 w1 = t1q[(size_t)s1 * 4 + q4];
        uint2 w2 = t1q[(size_t)s2 * 4 + q4];
        uint2 w3 = t1q[(size_t)s3 * 4 + q4];
        uint2 w4 = t1q[(size_t)s4 * 4 + q4];
        uint2 w5 = t1q[(size_t)s5 * 4 + q4];
        uint2 w6 = t1q[(size_t)s6 * 4 + q4];
        uint2 w7 = t1q[(size_t)s7 * 4 + q4];
        cv.u = w0.x; a0 += (float)cv.h[0]; a1 += (float)cv.h[1];
        cv.u = w0.y; a2 += (float)cv.h[0]; a3 += (float)cv.h[1];
        cv.u = w1.x; a0 += (float)cv.h[0]; a1 += (float)cv.h[1];
        cv.u = w1.y; a2 += (float)cv.h[0]; a3 += (float)cv.h[1];
        cv.u = w2.x; a0 += (float)cv.h[0]; a1 += (float)cv.h[1];
        cv.u = w2.y; a2 += (float)cv.h[0]; a3 += (float)cv.h[1];
        cv.u = w3.x; a0 += (float)cv.h[0]; a1 += (float)cv.h[1];
        cv.u = w3.y; a2 += (float)cv.h[0]; a3 += (float)cv.h[1];
        cv.u = w4.x; a0 += (float)cv.h[0]; a1 += (float)cv.h[1];
        cv.u = w4.y; a2 += (float)cv.h[0]; a3 += (float)cv.h[1];
        cv.u = w5.x; a0 += (float)cv.h[0]; a1 += (float)cv.h[1];
        cv.u = w5.y; a2 += (float)cv.h[0]; a3 += (float)cv.h[1];
        cv.u = w6.x; a0 += (float)cv.h[0]; a1 += (float)cv.h[1];
        cv.u = w6.y; a2 += (float)cv.h[0]; a3 += (float)cv.h[1];
        cv.u = w7.x; a0 += (float)cv.h[0]; a1 += (float)cv.h[1];
        cv.u = w7.y; a2 += (float)cv.h[0]; a3 += (float)cv.h[1];
    }
    for (; i + 6 < c; i += 8) {
        unsigned s0 = srcs[p + i],     s1 = srcs[p + i + 2];
        unsigned s2 = srcs[p + i + 4], s3 = srcs[p + i + 6];
        uint2 w0 = t1q[(size_t)s0 * 4 + q4];
        uint2 w1 = t1q[(size_t)s1 * 4 + q4];
        uint2 w2 = t1q[(size_t)s2 * 4 + q4];
        uint2 w3 = t1q[(size_t)s3 * 4 + q4];
        cv.u = w0.x; a0 += (float)cv.h[0]; a1 += (float)cv.h[1];
        cv.u = w0.y; a2 += (float)cv.h[0]; a3 += (float)cv.h[1];
        cv.u = w1.x; a0 += (float)cv.h[0]; a1 += (float)cv.h[1];
        cv.u = w1.y; a2 += (float)cv.h[0]; a3 += (float)cv.h[1];
        cv.u = w2.x; a0 += (float)cv.h[0]; a1 += (float)cv.h[1];
        cv.u = w2.y; a2 += (float)cv.h[0]; a3 += (float)cv.h[1];
        cv.u = w3.x; a0 += (float)cv.h[0]; a1 += (float)cv.h[1];
        cv.u = w3.y; a2 += (float)cv.h[0]; a3 += (float)cv.h[1];
    }
    for (; i + 2 < c; i += 4) {
        uint2 w0 = t1q[(size_t)srcs[p + i] * 4 + q4];
        uint2 w1 = t1q[(size_t)srcs[p + i + 2] * 4 + q4];
        cv.u = w0.x; a0 += (float)cv.h[0]; a1 += (float)cv.h[1];
        cv.u = w0.y; a2 += (float)cv.h[0]; a3 += (float)cv.h[1];
        cv.u = w1.x; a0 += (float)cv.h[0]; a1 += (float)cv.h[1];
        cv.u = w1.y; a2 += (float)cv.h[0]; a3 += (float)cv.h[1];
    }
    if (i < c) {
        uint2 w = t1q[(size_t)srcs[p + i] * 4 + q4];
        cv.u = w.x; a0 += (float)cv.h[0]; a1 += (float)cv.h[1];
        cv.u = w.y; a2 += (float)cv.h[0]; a3 += (float)cv.h[1];
    }
    // merge edge-parity halves (all 8 lanes alive)
    a0 += __shfl_xor(a0, 4, 64);
    a1 += __shfl_xor(a1, 4, 64);
    a2 += __shfl_xor(a2, 4, 64);
    a3 += __shfl_xor(a3, 4, 64);
    // self loop (both halves compute identically)
    uint2 sl = t1q[(size_t)d * 4 + q4];
    cv.u = sl.x; a0 += (float)cv.h[0]; a1 += (float)cv.h[1];
    cv.u = sl.y; a2 += (float)cv.h[0]; a3 += (float)cv.h[1];
    float di = rsqrtf((float)(c + 1u));
    float h0 = fmaxf(di * a0 + b1s[4 * q4 + 0], 0.f);
    float h1 = fmaxf(di * a1 + b1s[4 * q4 + 1], 0.f);
    float h2 = fmaxf(di * a2 + b1s[4 * q4 + 2], 0.f);
    float h3 = fmaxf(di * a3 + b1s[4 * q4 + 3], 0.f);
    // GEMM2 partials: this lane covers k = 4q4..4q4+3
    float o[NCLS];
#pragma unroll
    for (int cc = 0; cc < NCLS; ++cc)
        o[cc] = h0 * w2s[(4 * q4 + 0) * NCLS + cc] + h1 * w2s[(4 * q4 + 1) * NCLS + cc]
              + h2 * w2s[(4 * q4 + 2) * NCLS + cc] + h3 * w2s[(4 * q4 + 3) * NCLS + cc];
    // butterfly over the 4-lane quad (both parity halves redundantly)
#pragma unroll
    for (int m = 1; m < 4; m <<= 1)
#pragma unroll
        for (int cc = 0; cc < NCLS; ++cc)
            o[cc] += __shfl_xor(o[cc], m, 64);
    if (pr == 0) {
        union { unsigned u; h2v h; } pk;
        pk.h[0] = (_Float16)(o[2 * q4] * di);
        pk.h[1] = (_Float16)(o[2 * q4 + 1] * di);
        t2h[(size_t)d * 4 + q4] = pk.u;
    }
}

// ---------- conv2: 4 lanes/dst, uint2 gathers, 8-deep, fused mean-pool -------
__global__ void __launch_bounds__(256) k_agg2pool(const unsigned* __restrict__ srcs,
                                                  const unsigned* __restrict__ off,
                                                  const unsigned* __restrict__ degc,
                                                  const uint2* __restrict__ t2q,  // [n*2] uint2
                                                  const float* __restrict__ b2,
                                                  const int* __restrict__ batch,
                                                  float* __restrict__ out,
                                                  float* __restrict__ cg, int n) {
    __shared__ float wacc[WIN * NCLS];
    __shared__ float wcnt[WIN];
    __shared__ int gb_s;
    int t = threadIdx.x;
    int bbase = blockIdx.x * 64;
    if (t < WIN * NCLS) wacc[t] = 0.f;
    if (t < WIN) wcnt[t] = 0.f;
    if (t == 0) gb_s = batch[bbase < n ? bbase : (n - 1)];
    __syncthreads();
    int d = bbase + (t >> 2);
    int q2 = t & 1;                // uint2 index (features 4q2..4q2+3)
    int pr = (t >> 1) & 1;         // edge parity
    if (d < n) {
        unsigned p = off[d];
        unsigned c = degc[d];
        float a0 = 0.f, a1 = 0.f, a2 = 0.f, a3 = 0.f;
        union { unsigned u; h2v h; } cv;
        unsigned i = pr;
        for (; i + 14 < c; i += 16) {
            uint2 w0 = t2q[(size_t)srcs[p + i] * 2 + q2];
            uint2 w1 = t2q[(size_t)srcs[p + i + 2] * 2 + q2];
            uint2 w2 = t2q[(size_t)srcs[p + i + 4] * 2 + q2];
            uint2 w3 = t2q[(size_t)srcs[p + i + 6] * 2 + q2];
            uint2 w4 = t2q[(size_t)srcs[p + i + 8] * 2 + q2];
            uint2 w5 = t2q[(size_t)srcs[p + i + 10] * 2 + q2];
            uint2 w6 = t2q[(size_t)srcs[p + i + 12] * 2 + q2];
            uint2 w7 = t2q[(size_t)srcs[p + i + 14] * 2 + q2];
            cv.u = w0.x; a0 += (float)cv.h[0]; a1 += (float)cv.h[1];
            cv.u = w0.y; a2 += (float)cv.h[0]; a3 += (float)cv.h[1];
            cv.u = w1.x; a0 += (float)cv.h[0]; a1 += (float)cv.h[1];
            cv.u = w1.y; a2 += (float)cv.h[0]; a3 += (float)cv.h[1];
            cv.u = w2.x; a0 += (float)cv.h[0]; a1 += (float)cv.h[1];
            cv.u = w2.y; a2 += (float)cv.h[0]; a3 += (float)cv.h[1];
            cv.u = w3.x; a0 += (float)cv.h[0]; a1 += (float)cv.h[1];
            cv.u = w3.y; a2 += (float)cv.h[0]; a3 += (float)cv.h[1];
            cv.u = w4.x; a0 += (float)cv.h[0]; a1 += (float)cv.h[1];
            cv.u = w4.y; a2 += (float)cv.h[0]; a3 += (float)cv.h[1];
            cv.u = w5.x; a0 += (float)cv.h[0]; a1 += (float)cv.h[1];
            cv.u = w5.y; a2 += (float)cv.h[0]; a3 += (float)cv.h[1];
            cv.u = w6.x; a0 += (float)cv.h[0]; a1 += (float)cv.h[1];
            cv.u = w6.y; a2 += (float)cv.h[0]; a3 += (float)cv.h[1];
            cv.u = w7.x; a0 += (float)cv.h[0]; a1 += (float)cv.h[1];
            cv.u = w7.y; a2 += (float)cv.h[0]; a3 += (float)cv.h[1];
        }
        for (; i + 6 < c; i += 8) {
            uint2 w0 = t2q[(size_t)srcs[p + i] * 2 + q2];
            uint2 w1 = t2q[(size_t)srcs[p + i + 2] * 2 + q2];
            uint2 w2 = t2q[(size_t)srcs[p + i + 4] * 2 + q2];
            uint2 w3 = t2q[(size_t)srcs[p + i + 6] * 2 + q2];
            cv.u = w0.x; a0 += (float)cv.h[0]; a1 += (float)cv.h[1];
            cv.u = w0.y; a2 += (float)cv.h[0]; a3 += (float)cv.h[1];
            cv.u = w1.x; a0 += (float)cv.h[0]; a1 += (float)cv.h[1];
            cv.u = w1.y; a2 += (float)cv.h[0]; a3 += (float)cv.h[1];
            cv.u = w2.x; a0 += (float)cv.h[0]; a1 += (float)cv.h[1];
            cv.u = w2.y; a2 += (float)cv.h[0]; a3 += (float)cv.h[1];
            cv.u = w3.x; a0 += (float)cv.h[0]; a1 += (float)cv.h[1];
            cv.u = w3.y; a2 += (float)cv.h[0]; a3 += (float)cv.h[1];
        }
        for (; i + 2 < c; i += 4) {
            uint2 w0 = t2q[(size_t)srcs[p + i] * 2 + q2];
            uint2 w1 = t2q[(size_t)srcs[p + i + 2] * 2 + q2];
            cv.u = w0.x; a0 += (float)cv.h[0]; a1 += (float)cv.h[1];
            cv.u = w0.y; a2 += (float)cv.h[0]; a3 += (float)cv.h[1];
            cv.u = w1.x; a0 += (float)cv.h[0]; a1 += (float)cv.h[1];
            cv.u = w1.y; a2 += (float)cv.h[0]; a3 += (float)cv.h[1];
        }
        if (i < c) {
            uint2 w = t2q[(size_t)srcs[p + i] * 2 + q2];
            cv.u = w.x; a0 += (float)cv.h[0]; a1 += (float)cv.h[1];
            cv.u = w.y; a2 += (float)cv.h[0]; a3 += (float)cv.h[1];
        }
        a0 += __shfl_xor(a0, 2, 64);
        a1 += __shfl_xor(a1, 2, 64);
        a2 += __shfl_xor(a2, 2, 64);
        a3 += __shfl_xor(a3, 2, 64);
        if (pr == 0) {
            uint2 sl = t2q[(size_t)d * 2 + q2];  // self loop
            cv.u = sl.x; a0 += (float)cv.h[0]; a1 += (float)cv.h[1];
            cv.u = sl.y; a2 += (float)cv.h[0]; a3 += (float)cv.h[1];
            float di = rsqrtf((float)(c + 1u));
            int f0 = 4 * q2;
            float v0 = di * a0 + b2[f0 + 0];
            float v1 = di * a1 + b2[f0 + 1];
            float v2 = di * a2 + b2[f0 + 2];
            float v3 = di * a3 + b2[f0 + 3];
            int g = batch[d];
            int gi = g - gb_s;
            if (gi < WIN) {
                atomicAdd(&wacc[gi * NCLS + f0 + 0], v0);
                atomicAdd(&wacc[gi * NCLS + f0 + 1], v1);
                atomicAdd(&wacc[gi * NCLS + f0 + 2], v2);
                atomicAdd(&wacc[gi * NCLS + f0 + 3], v3);
                if ((t & 3) == 0) atomicAdd(&wcnt[gi], 1.f);
            } else {
                atomicAdd(&out[(size_t)g * NCLS + f0 + 0], v0);
                atomicAdd(&out[(size_t)g * NCLS + f0 + 1], v1);
                atomicAdd(&out[(size_t)g * NCLS + f0 + 2], v2);
                atomicAdd(&out[(size_t)g * NCLS + f0 + 3], v3);
                if ((t & 3) == 0) atomicAdd(&cg[g], 1.f);
            }
        }
    }
    __syncthreads();
    if (t < WIN * NCLS && wcnt[t >> 3] > 0.f)
        atomicAdd(&out[(size_t)(gb_s + (t >> 3)) * NCLS + (t & 7)], wacc[t]);
    if (t < WIN && wcnt[t] > 0.f) atomicAdd(&cg[gb_s + t], wcnt[t]);
}

__global__ void k_div(float* __restrict__ out, const float* __restrict__ cg, int total) {
    int i = blockIdx.x * blockDim.x + threadIdx.x;
    if (i < total) out[i] /= fmaxf(cg[i / NCLS], 1.0f);
}

extern "C" void kernel_launch(void* const* d_in, const int* in_sizes, int n_in,
                              void* d_out, int out_size, void* d_ws, size_t ws_size,
                              hipStream_t stream) {
    const float* x = (const float*)d_in[0];
    const int* ei = (const int*)d_in[1];
    const int* batch = (const int*)d_in[2];
    const float* W1 = (const float*)d_in[4];
    const float* b1 = (const float*)d_in[5];
    const float* W2 = (const float*)d_in[6];
    const float* b2 = (const float*)d_in[7];

    int n = in_sizes[0] / F_IN;
    int e = in_sizes[1] / 2;
    int g = out_size / NCLS;
    const int* src = ei;
    const int* dst = ei + e;
    int nbins = (n + NPB - 1) >> BSH;  // 196 for n=100000

    char* w = (char*)d_ws;
    unsigned* binCur = (unsigned*)w; w += (size_t)MAXBINS * 4;
    unsigned* degc   = (unsigned*)w; w += (size_t)n * 4;
    unsigned* off    = (unsigned*)w; w += (size_t)n * 4;
    unsigned* t1h    = (unsigned*)w; w += (size_t)n * 8 * 4;   // fp16 pairs, 3.2 MB
    unsigned* t2h    = (unsigned*)w; w += (size_t)n * 4 * 4;   // fp16 pairs, 1.6 MB
    _Float16* wfrag  = (_Float16*)w; w += (size_t)64 * 8 * 8 * 2;  // 8 KB
    float* cg        = (float*)w;    w += (size_t)g * 4;
    w = (char*)(((size_t)w + 255) & ~(size_t)255);
    unsigned* binbuf = (unsigned*)w; w += (size_t)nbins * BCAP * 4;  // 14.5 MB
    unsigned* srcs   = (unsigned*)w; w += (size_t)nbins * BCAP * 4;  // 14.5 MB

    k_init<<<1, 256, 0, stream>>>(binCur, nbins, W1, wfrag, cg, g, (float*)d_out, out_size);
    k_binA<<<(e + TILE - 1) / TILE, 512, 0, stream>>>(src, dst, e, binCur, binbuf);
    k_binB<<<nbins, 256, 0, stream>>>(binbuf, binCur, n, srcs, off, degc);
    k_gemm1<<<(n + GROWS - 1) / GROWS, 256, 0, stream>>>(x, wfrag, degc, (_Float16*)t1h, n);
    k_agg1g2<<<(n + 31) / 32, 256, 0, stream>>>(srcs, off, degc, (const uint2*)t1h,
                                                b1, W2, t2h, n);
    k_agg2pool<<<(n + 63) / 64, 256, 0, stream>>>(srcs, off, degc, (const uint2*)t2h,
                                                  b2, batch, (float*)d_out, cg, n);
    k_div<<<(out_size + 255) / 256, 256, 0, stream>>>((float*)d_out, cg, out_size);
}